// Round 16
// baseline (387.359 us; speedup 1.0000x reference)
//
#include <hip/hip_runtime.h>
#include <hip/hip_bf16.h>
#include <hip/hip_cooperative_groups.h>

namespace cg = cooperative_groups;

// Inputs/outputs are f32 (proven: round-5 bf16 -> NaN; rounds 4/6 passed on f32 path).
// Round 14: cooperative @512 blocks rejected (zero output). This round: cooperative
// @256 blocks (1 block/CU, co-residency guaranteed) WITH runtime fallback to the
// proven 5-kernel path if hipLaunchCooperativeKernel returns an error.

#define NS   4
#define NPX  4096
#define NSZ  24
#define PS   64
#define VINW 520   // ch map: 0-255 ictx, 256-511 pf, 512-514 blended, 515-519 pad
#define HW   34    // half-row LDS width: 32 cols + 2-col halo

#define OFF0 0        // ref_novel_view (3,4096)
#define OFF1 12288    // blended_img    (3,4096)
#define OFF2 24576    // interp_view    (4,3,4096)
#define OFF3 73728    // weight         (4,4096,24)
#define OFF4 466944   // confs          (4,4096)

// ---------------------------------------------------------------------------
__device__ unsigned g_cc [NS * NPX * 64];   // [s][p][ch]: lo=ce, hi=ctx (bf16)
__device__ float2 g_fld[NS * NPX];          // per-pixel (Aw, Ac) score fields
__device__ float2 g_sa [NS * NPX * NSZ];    // per-(s,p,n) spa/ang logit terms
__device__ __align__(16) unsigned short g_vin [NPX * VINW];  // bf16
__device__ float g_iv  [NS * NPX * 3];
__device__ float g_clg [NS * NPX];
__device__ float g_fwT [162 * 64];
__device__ float g_cwT [27 * 64];
__device__ float g_pwT [54 * 64];
__device__ __align__(16) unsigned short g_vwT [3 * 9 * VINW];

__device__ __forceinline__ int clampi(int v, int lo, int hi) {
    return v < lo ? lo : (v > hi ? hi : v);
}
__device__ __forceinline__ unsigned bf16_bits(float f) {
    unsigned u = __float_as_uint(f);
    return (u + 0x7fffu + ((u >> 16) & 1u)) >> 16;
}
__device__ __forceinline__ float bf16_lo(unsigned v) { return __uint_as_float(v << 16); }
__device__ __forceinline__ float bf16_hi(unsigned v) { return __uint_as_float(v & 0xffff0000u); }
__device__ __forceinline__ float ldbf(const unsigned short* p, int i) {
    return __uint_as_float(((unsigned)p[i]) << 16);
}

struct Params {
    const float *sv, *sf, *psvs, *wv;
    const int   *nxy;
    const float *spa, *ang;
    const float *fw, *fb, *cw, *cb;
    const float *ww, *wb, *cnw, *cnb;
    const float *pw, *pb, *vw, *vb;
    float *out;
};

// ======================= device phase bodies (shared) =======================

__device__ __forceinline__ void prep_body(const Params& P, int i, int stride)
{
    for (int d = i; d < 162 * 64; d += stride) g_fwT[d] = P.fw[(d & 63) * 162 + (d >> 6)];
    for (int d = i; d < 27 * 64;  d += stride) g_cwT[d] = P.cw[(d & 63) * 27  + (d >> 6)];
    for (int d = i; d < 54 * 64;  d += stride) g_pwT[d] = P.pw[(d & 63) * 54  + (d >> 6)];
    for (int d = i; d < 3 * 9 * VINW; d += stride) {
        const int oc = d / (9 * VINW), rem = d % (9 * VINW);
        const int t = rem / VINW, nch = rem % VINW;
        float v = 0.f;
        if (nch < 256)      v = P.vw[(oc * 515 + 3 + nch) * 9 + t];
        else if (nch < 512) v = P.vw[(oc * 515 + 259 + (nch - 256)) * 9 + t];
        else if (nch < 515) v = P.vw[(oc * 515 + (nch - 512)) * 9 + t];
        g_vwT[d] = (unsigned short)bf16_bits(v);
    }
    for (int d = i; d < NS * NPX; d += stride) {
        const int s = d >> 12, p = d & 4095;
        float2 acc[NSZ];
        #pragma unroll
        for (int n = 0; n < NSZ; ++n) acc[n] = make_float2(0.f, 0.f);
        #pragma unroll
        for (int c = 0; c < 2; ++c) {
            const float a = P.ww[198 + c], b = P.cnw[198 + c];
            #pragma unroll
            for (int n = 0; n < NSZ; ++n) {
                const float v = P.spa[((s * 2 + c) * NSZ + n) * NPX + p];
                acc[n].x += v * a;
                acc[n].y += v * b;
            }
        }
        #pragma unroll
        for (int c = 0; c < 6; ++c) {
            const float a = P.ww[200 + c], b = P.cnw[200 + c];
            #pragma unroll
            for (int n = 0; n < NSZ; ++n) {
                const float v = P.ang[((s * 6 + c) * NSZ + n) * NPX + p];
                acc[n].x += v * a;
                acc[n].y += v * b;
            }
        }
        float2* dst = g_sa + (size_t)(s * NPX + p) * NSZ;
        #pragma unroll
        for (int n = 0; n < NSZ; ++n) dst[n] = acc[n];
    }
}

// conv phase for one (s,py,half) tile; lds must hold >= 18*3*HW floats
__device__ __forceinline__ void convs_body(const Params& P, float* lds, int b2, int tid)
{
    const int s = b2 >> 7, py = (b2 & 127) >> 1, half = b2 & 1;

    for (int i = tid; i < 18 * 3 * HW; i += 256) {
        const int lc = i % HW;
        const int rr = (i / HW) % 3;
        const int pl = i / (3 * HW);
        const int iy = py + rr - 1;
        const int ix = half * 32 + lc - 1;
        float v = 0.f;
        if ((unsigned)iy < 64u && (unsigned)ix < 64u) {
            const float* src = (pl < 6) ? (P.sf + (s * 6 + pl) * NPX)
                             : (pl < 9) ? (P.sv + (s * 3 + (pl - 6)) * NPX)
                                        : (P.wv + (s * 9 + (pl - 9)) * NPX);
            v = src[iy * 64 + ix];
        }
        lds[i] = v;
    }
    __syncthreads();

    const int oc  = tid & 63;
    const int wid = tid >> 6;
    const int lc0 = wid * 8;

    float acc_ce[8], acc_ctx[8];
    const float fb = P.fb[oc], cb = P.cb[oc];
    #pragma unroll
    for (int j = 0; j < 8; ++j) { acc_ce[j] = fb; acc_ctx[j] = cb; }

    for (int pl = 0; pl < 18; ++pl) {
        float w[9];
        #pragma unroll
        for (int t = 0; t < 9; ++t) w[t] = g_fwT[(pl * 9 + t) * 64 + oc];
        float wc[9];
        const bool has_ctx = (pl >= 6 && pl < 9);
        if (has_ctx) {
            #pragma unroll
            for (int t = 0; t < 9; ++t) wc[t] = g_cwT[((pl - 6) * 9 + t) * 64 + oc];
        }
        float c0[3], c1[3], c2[3];
        #pragma unroll
        for (int r = 0; r < 3; ++r) {
            c0[r] = lds[(pl * 3 + r) * HW + lc0];
            c1[r] = lds[(pl * 3 + r) * HW + lc0 + 1];
        }
        #pragma unroll
        for (int j = 0; j < 8; ++j) {
            #pragma unroll
            for (int r = 0; r < 3; ++r)
                c2[r] = lds[(pl * 3 + r) * HW + lc0 + j + 2];
            float a = 0.f;
            #pragma unroll
            for (int r = 0; r < 3; ++r)
                a += c0[r] * w[r * 3 + 0] + c1[r] * w[r * 3 + 1] + c2[r] * w[r * 3 + 2];
            acc_ce[j] += a;
            if (has_ctx) {
                float b2f = 0.f;
                #pragma unroll
                for (int r = 0; r < 3; ++r)
                    b2f += c0[r] * wc[r * 3 + 0] + c1[r] * wc[r * 3 + 1] + c2[r] * wc[r * 3 + 2];
                acc_ctx[j] += b2f;
            }
            #pragma unroll
            for (int r = 0; r < 3; ++r) { c0[r] = c1[r]; c1[r] = c2[r]; }
        }
    }

    const float Wce = P.ww[6 + oc], Cce = P.cnw[6 + oc];
    float awsel = 0.f, acsel = 0.f;
    #pragma unroll
    for (int j = 0; j < 8; ++j) {
        const float ce = fmaxf(acc_ce[j], 0.f);
        const float cx = fmaxf(acc_ctx[j], 0.f);
        const int p = py * 64 + half * 32 + wid * 8 + j;
        g_cc[(s * NPX + p) * 64 + oc] = bf16_bits(ce) | (bf16_bits(cx) << 16);
        float gw = ce * Wce, gc = ce * Cce;
        #pragma unroll
        for (int off = 32; off; off >>= 1) {
            gw += __shfl_xor(gw, off, 64);
            gc += __shfl_xor(gc, off, 64);
        }
        awsel = (oc == j) ? gw : awsel;
        acsel = (oc == j) ? gc : acsel;
    }
    if (oc < 8) {
        const int lpx = wid * 8 + oc;
        float fwv = 0.f, fcv = 0.f;
        #pragma unroll
        for (int c = 0; c < 6; ++c) {
            const float v = lds[(c * 3 + 1) * HW + lpx + 1];
            fwv += v * P.ww[c];
            fcv += v * P.cnw[c];
        }
        g_fld[s * NPX + py * 64 + half * 32 + lpx] = make_float2(awsel + fwv, acsel + fcv);
    }
}

// epi phase for one (s, p) per wave
__device__ __forceinline__ void epi_body(const Params& P, int s, int p, int l)
{
    int q[NSZ];
    #pragma unroll
    for (int e = 0; e < 8; ++e) {
        int nx = P.nxy[((s * NPX + p) * 8 + e) * 2 + 0];
        int ny = P.nxy[((s * NPX + p) * 8 + e) * 2 + 1];
        nx = clampi(nx, 0, 63);
        #pragma unroll
        for (int k = 0; k < 3; ++k) {
            int y = clampi(ny + k - 1, 0, 63);
            q[e * 3 + k] = y * 64 + nx;
        }
    }

    const unsigned* ccp = g_cc + (size_t)s * NPX * 64;
    unsigned cc[NSZ];
    #pragma unroll
    for (int n = 0; n < NSZ; ++n) cc[n] = ccp[q[n] * 64 + l];

    float mu = 0.f;
    #pragma unroll
    for (int n = 0; n < NSZ; ++n) mu += bf16_lo(cc[n]);
    mu *= (1.f / 24.f);
    float var = 0.f;
    #pragma unroll
    for (int n = 0; n < NSZ; ++n) { const float d = bf16_lo(cc[n]) - mu; var += d * d; }
    var *= (1.f / 23.f);

    float pw = mu * P.ww[70 + l] + var * P.ww[134 + l];
    float pc = mu * P.cnw[70 + l] + var * P.cnw[134 + l];
    #pragma unroll
    for (int off = 32; off; off >>= 1) {
        pw += __shfl_xor(pw, off, 64);
        pc += __shfl_xor(pc, off, 64);
    }
    const float base_w = pw, base_c = pc;

    float Aw = 0.f, Ac = 0.f;
    if (l < NSZ) {
        const float2 A = g_fld[s * NPX + q[l]];
        const float2 B = g_sa[(size_t)(s * NPX + p) * NSZ + l];
        Aw = A.x + B.x; Ac = A.y + B.y;
    }

    float logit = (l < NSZ) ? (Aw + base_w + P.wb[0]) : -1e30f;
    float mx = logit;
    #pragma unroll
    for (int off = 32; off; off >>= 1) mx = fmaxf(mx, __shfl_xor(mx, off, 64));
    float e = (l < NSZ) ? __expf(logit - mx) : 0.f;
    float ssum = e;
    #pragma unroll
    for (int off = 32; off; off >>= 1) ssum += __shfl_xor(ssum, off, 64);
    const float wgt = e / ssum;

    float clp = (l < NSZ) ? (Ac + base_c) * wgt : 0.f;
    #pragma unroll
    for (int off = 32; off; off >>= 1) clp += __shfl_xor(clp, off, 64);
    if (l == 0) g_clg[s * NPX + p] = clp;

    if (l < NSZ) P.out[OFF3 + (s * NPX + p) * NSZ + l] = wgt;

    float wall[NSZ];
    #pragma unroll
    for (int n = 0; n < NSZ; ++n) wall[n] = __shfl(wgt, n, 64);

    float sc = 0.f;
    #pragma unroll
    for (int n = 0; n < NSZ; ++n) sc += bf16_hi(cc[n]) * wall[n];
    g_vin[p * VINW + s * 64 + l] = (unsigned short)bf16_bits(sc);

    if (l < 3) {
        float svv = 0.f;
        #pragma unroll
        for (int n = 0; n < NSZ; ++n) svv += P.sv[(s * 3 + l) * NPX + q[n]] * wall[n];
        g_iv[(s * NPX + p) * 3 + l] = svv;
        P.out[OFF2 + (s * 3 + l) * NPX + p] = svv;
    }
}

// psv + fused conf/blend phase for one (s,py,half) tile
__device__ __forceinline__ void psv_body(const Params& P, float* lds, int b2, int tid)
{
    const int s = b2 >> 7, py = (b2 & 127) >> 1, half = b2 & 1;

    for (int i = tid; i < 27 * 3 * HW; i += 256) {
        const int lc = i % HW;
        const int rr = (i / HW) % 3;
        const int pl = i / (3 * HW);
        float v = 0.f;
        if (pl < 24) {
            const int iy = py + rr - 1;
            const int ix = half * 32 + lc - 1;
            if ((unsigned)iy < 64u && (unsigned)ix < 64u)
                v = P.psvs[(s * 24 + pl) * NPX + iy * 64 + ix];
        }
        lds[i] = v;
    }
    __syncthreads();

    if (tid < 3 * HW) {
        const int r = tid / HW, lc = tid % HW;
        const int iy = py + r - 1, ix = half * 32 + lc - 1;
        if ((unsigned)iy < 64u && (unsigned)ix < 64u) {
            const int p = iy * 64 + ix;
            const float cb2 = P.cnb[0];
            float lg[NS];
            #pragma unroll
            for (int ss = 0; ss < NS; ++ss) lg[ss] = g_clg[ss * NPX + p] + cb2;
            float m = lg[0];
            #pragma unroll
            for (int ss = 1; ss < NS; ++ss) m = fmaxf(m, lg[ss]);
            float ssum = 0.f;
            float conf[NS];
            #pragma unroll
            for (int ss = 0; ss < NS; ++ss) { conf[ss] = __expf(lg[ss] - m); ssum += conf[ss]; }
            const float inv = 1.f / ssum;
            #pragma unroll
            for (int ss = 0; ss < NS; ++ss) conf[ss] *= inv;
            float bl[3];
            #pragma unroll
            for (int c = 0; c < 3; ++c) {
                float a = 0.f;
                #pragma unroll
                for (int ss = 0; ss < NS; ++ss)
                    a += g_iv[(ss * NPX + p) * 3 + c] * conf[ss];
                bl[c] = a;
                lds[((24 + c) * 3 + r) * HW + lc] = a;
            }
            if (s == 0 && r == 1 && lc >= 1 && lc <= 32) {
                #pragma unroll
                for (int ss = 0; ss < NS; ++ss) P.out[OFF4 + ss * NPX + p] = conf[ss];
                #pragma unroll
                for (int c = 0; c < 3; ++c) {
                    P.out[OFF1 + c * NPX + p] = bl[c];
                    g_vin[p * VINW + 512 + c] = (unsigned short)bf16_bits(bl[c]);
                }
            }
        }
    }
    __syncthreads();

    const int oc  = tid & 63;
    const int wid = tid >> 6;
    const int lc0 = wid * 8;
    const float bias = P.pb[oc];

    float wp[3][9];
    #pragma unroll
    for (int ic = 0; ic < 3; ++ic)
        #pragma unroll
        for (int t = 0; t < 9; ++t) wp[ic][t] = g_pwT[(ic * 9 + t) * 64 + oc];

    float bconst[8];
    #pragma unroll
    for (int j = 0; j < 8; ++j) bconst[j] = bias;
    for (int ic = 0; ic < 3; ++ic) {
        float w[9];
        #pragma unroll
        for (int t = 0; t < 9; ++t) w[t] = g_pwT[((3 + ic) * 9 + t) * 64 + oc];
        const int pl = 24 + ic;
        float c0[3], c1[3], c2[3];
        #pragma unroll
        for (int r = 0; r < 3; ++r) {
            c0[r] = lds[(pl * 3 + r) * HW + lc0];
            c1[r] = lds[(pl * 3 + r) * HW + lc0 + 1];
        }
        #pragma unroll
        for (int j = 0; j < 8; ++j) {
            #pragma unroll
            for (int r = 0; r < 3; ++r)
                c2[r] = lds[(pl * 3 + r) * HW + lc0 + j + 2];
            float a = 0.f;
            #pragma unroll
            for (int r = 0; r < 3; ++r)
                a += c0[r] * w[r * 3 + 0] + c1[r] * w[r * 3 + 1] + c2[r] * w[r * 3 + 2];
            bconst[j] += a;
            #pragma unroll
            for (int r = 0; r < 3; ++r) { c0[r] = c1[r]; c1[r] = c2[r]; }
        }
    }

    float acc[8];
    #pragma unroll
    for (int j = 0; j < 8; ++j) acc[j] = 0.f;

    for (int d = 0; d < 8; ++d) {
        float a[8];
        #pragma unroll
        for (int j = 0; j < 8; ++j) a[j] = bconst[j];
        #pragma unroll
        for (int ic = 0; ic < 3; ++ic) {
            const int pl = ic * 8 + d;
            float c0[3], c1[3], c2[3];
            #pragma unroll
            for (int r = 0; r < 3; ++r) {
                c0[r] = lds[(pl * 3 + r) * HW + lc0];
                c1[r] = lds[(pl * 3 + r) * HW + lc0 + 1];
            }
            #pragma unroll
            for (int j = 0; j < 8; ++j) {
                #pragma unroll
                for (int r = 0; r < 3; ++r)
                    c2[r] = lds[(pl * 3 + r) * HW + lc0 + j + 2];
                float t2 = 0.f;
                #pragma unroll
                for (int r = 0; r < 3; ++r)
                    t2 += c0[r] * wp[ic][r * 3 + 0] + c1[r] * wp[ic][r * 3 + 1] + c2[r] * wp[ic][r * 3 + 2];
                a[j] += t2;
                #pragma unroll
                for (int r = 0; r < 3; ++r) { c0[r] = c1[r]; c1[r] = c2[r]; }
            }
        }
        #pragma unroll
        for (int j = 0; j < 8; ++j) acc[j] += fmaxf(a[j], 0.f);
    }
    #pragma unroll
    for (int j = 0; j < 8; ++j)
        g_vin[(py * 64 + half * 32 + wid * 8 + j) * VINW + 256 + s * 64 + oc] =
            (unsigned short)bf16_bits(acc[j] * 0.125f);
}

// vref for one pixel p per wave
__device__ __forceinline__ void vref_body(const Params& P, int p, int l)
{
    const int py = p >> 6, px = p & 63;
    float acc[3] = {0.f, 0.f, 0.f};
    #pragma unroll
    for (int t = 0; t < 9; ++t) {
        const int iy = py + t / 3 - 1, ix = px + t % 3 - 1;
        if ((unsigned)iy >= 64u || (unsigned)ix >= 64u) continue;
        const int rowbase = (iy * 64 + ix) * VINW;
        const uint4 vv = *(const uint4*)(g_vin + rowbase + 8 * l);
        float v[8];
        v[0] = bf16_lo(vv.x); v[1] = bf16_hi(vv.x);
        v[2] = bf16_lo(vv.y); v[3] = bf16_hi(vv.y);
        v[4] = bf16_lo(vv.z); v[5] = bf16_hi(vv.z);
        v[6] = bf16_lo(vv.w); v[7] = bf16_hi(vv.w);
        #pragma unroll
        for (int oc = 0; oc < 3; ++oc) {
            const uint4 ww = *(const uint4*)(g_vwT + (oc * 9 + t) * VINW + 8 * l);
            acc[oc] += v[0] * bf16_lo(ww.x) + v[1] * bf16_hi(ww.x)
                     + v[2] * bf16_lo(ww.y) + v[3] * bf16_hi(ww.y)
                     + v[4] * bf16_lo(ww.z) + v[5] * bf16_hi(ww.z)
                     + v[6] * bf16_lo(ww.w) + v[7] * bf16_hi(ww.w);
        }
        if (l < 3) {
            const float bv = ldbf(g_vin, rowbase + 512 + l);
            #pragma unroll
            for (int oc = 0; oc < 3; ++oc)
                acc[oc] += bv * ldbf(g_vwT, (oc * 9 + t) * VINW + 512 + l);
        }
    }
    #pragma unroll
    for (int off = 32; off; off >>= 1) {
        #pragma unroll
        for (int oc = 0; oc < 3; ++oc)
            acc[oc] += __shfl_xor(acc[oc], off, 64);
    }
    if (l == 0) {
        #pragma unroll
        for (int oc = 0; oc < 3; ++oc)
            P.out[OFF0 + oc * NPX + p] = acc[oc] + P.vb[oc];
    }
}

// ======================= fused cooperative kernel =======================
// 256 blocks x 256 threads = 1 block/CU (co-residency guaranteed).
__global__ __launch_bounds__(256, 1) void k_all(Params P)
{
    cg::grid_group grid = cg::this_grid();
    __shared__ float lds[27 * 3 * HW];

    const int b   = blockIdx.x;       // [0,256)
    const int tid = threadIdx.x;
    const int l   = tid & 63;
    const int wid = tid >> 6;

    prep_body(P, b * 256 + tid, 256 * 256);
    grid.sync();

    #pragma unroll
    for (int u = 0; u < 2; ++u) {
        convs_body(P, lds, b * 2 + u, tid);
        __syncthreads();
    }
    grid.sync();

    {
        const int bs = b & 7, hi = b >> 3;            // hi in [0,32)
        const int s = bs >> 1, parity = bs & 1;       // XCD source affinity kept
        for (int it = 0; it < 16; ++it) {
            const int p = (hi * 16 + it) * 8 + parity * 4 + wid;
            epi_body(P, s, p, l);
        }
    }
    grid.sync();

    #pragma unroll
    for (int u = 0; u < 2; ++u) {
        psv_body(P, lds, b * 2 + u, tid);
        __syncthreads();
    }
    grid.sync();

    {
        const int wg = b * 4 + wid;                   // [0,1024)
        #pragma unroll
        for (int j = 0; j < 4; ++j)
            vref_body(P, wg * 4 + j, l);
    }
}

// ======================= standalone fallback kernels =======================

__global__ __launch_bounds__(256) void k_prep(Params P)
{
    prep_body(P, blockIdx.x * 256 + threadIdx.x, gridDim.x * 256);
}

__global__ __launch_bounds__(256) void k_convs(Params P)
{
    __shared__ float lds[18 * 3 * HW];
    convs_body(P, lds, blockIdx.x, threadIdx.x);
}

__global__ __launch_bounds__(256) void k_epi(Params P)
{
    const int blk = blockIdx.x;
    const int wid = threadIdx.x >> 6;
    const int l   = threadIdx.x & 63;
    const int s   = (blk & 7) >> 1;
    const int p   = (blk >> 3) * 8 + (blk & 1) * 4 + wid;
    epi_body(P, s, p, l);
}

__global__ __launch_bounds__(256) void k_psv(Params P)
{
    __shared__ float lds[27 * 3 * HW];
    psv_body(P, lds, blockIdx.x, threadIdx.x);
}

__global__ __launch_bounds__(64) void k_vref(Params P)
{
    vref_body(P, blockIdx.x, threadIdx.x);
}

// ---------------------------------------------------------------------------
extern "C" void kernel_launch(void* const* d_in, const int* in_sizes, int n_in,
                              void* d_out, int out_size, void* d_ws, size_t ws_size,
                              hipStream_t stream)
{
    auto find1 = [&](int sz, int fb) -> int {
        for (int i = 0; i < n_in; ++i) if (in_sizes[i] == sz) return i;
        return fb;
    };
    const int i_sv  = find1(49152, 0);
    const int i_sf  = find1(98304, 1);
    const int i_psv = find1(393216, 2);
    const int i_wv  = find1(147456, 3);
    const int i_nxy = find1(262144, 5);
    const int i_spa = find1(786432, 6);
    const int i_ang = find1(2359296, 7);
    const int i_fw  = find1(10368, 9);
    const int i_cw  = find1(1728, 11);
    const int i_pw  = find1(3456, 17);
    const int i_vw  = find1(13905, 19);
    const int i_vb  = find1(3, 20);
    int i_ww = -1, i_cnw = -1;
    for (int i = 0; i < n_in; ++i)
        if (in_sizes[i] == 206) { if (i_ww < 0) i_ww = i; else { i_cnw = i; break; } }
    if (i_ww  < 0) i_ww  = 13;
    if (i_cnw < 0) i_cnw = 15;
    int b64[3] = {10, 12, 18}; int c64 = 0;
    for (int i = 0; i < n_in && c64 < 3; ++i) if (in_sizes[i] == 64) b64[c64++] = i;
    const int i_fb = b64[0], i_cb = b64[1], i_pb = b64[2];
    int i_wb = -1, i_cnb = -1;
    for (int i = i_fw + 1; i < n_in; ++i)
        if (in_sizes[i] == 1) { if (i_wb < 0) i_wb = i; else { i_cnb = i; break; } }
    if (i_wb  < 0) i_wb  = 14;
    if (i_cnb < 0) i_cnb = 16;

    Params P;
    P.sv   = (const float*)d_in[i_sv];
    P.sf   = (const float*)d_in[i_sf];
    P.psvs = (const float*)d_in[i_psv];
    P.wv   = (const float*)d_in[i_wv];
    P.nxy  = (const int*)d_in[i_nxy];
    P.spa  = (const float*)d_in[i_spa];
    P.ang  = (const float*)d_in[i_ang];
    P.fw   = (const float*)d_in[i_fw];
    P.fb   = (const float*)d_in[i_fb];
    P.cw   = (const float*)d_in[i_cw];
    P.cb   = (const float*)d_in[i_cb];
    P.ww   = (const float*)d_in[i_ww];
    P.wb   = (const float*)d_in[i_wb];
    P.cnw  = (const float*)d_in[i_cnw];
    P.cnb  = (const float*)d_in[i_cnb];
    P.pw   = (const float*)d_in[i_pw];
    P.pb   = (const float*)d_in[i_pb];
    P.vw   = (const float*)d_in[i_vw];
    P.vb   = (const float*)d_in[i_vb];
    P.out  = (float*)d_out;
    (void)d_ws; (void)ws_size; (void)out_size;

    void* args[] = { &P };
    hipError_t err = hipLaunchCooperativeKernel((void*)k_all, dim3(256), dim3(256),
                                                args, 0, stream);
    if (err != hipSuccess) {
        // fallback: proven 5-kernel path (identical results, same scratch writes)
        k_prep <<<64, 256, 0, stream>>>(P);
        k_convs<<<512, 256, 0, stream>>>(P);
        k_epi  <<<4096, 256, 0, stream>>>(P);
        k_psv  <<<512, 256, 0, stream>>>(P);
        k_vref <<<4096, 64, 0, stream>>>(P);
    }
}

// Round 17
// 176.445 us; speedup vs baseline: 2.1954x; 2.1954x over previous
//
#include <hip/hip_runtime.h>
#include <hip/hip_bf16.h>

// Inputs/outputs are f32 (proven: round-5 bf16 -> NaN; rounds 4/6 passed on f32 path).
// Round 14 (coop @512): launch rejected. Round 16 (coop @256): accepted but 2.2x SLOWER
// (VGPR 204, 1 block/CU -> occupancy collapse in the gather phase). Launch fusion is
// closed. This is the exact round-13 configuration — best measured state (175.3 us).

// problem constants (fixed by harness shapes)
#define NS   4
#define NPX  4096
#define NSZ  24
#define PS   64
#define VINW 520   // ch map: 0-255 ictx, 256-511 pf, 512-514 blended, 515-519 pad
#define HW   34    // half-row LDS width: 32 cols + 2-col halo

// out element offsets
#define OFF0 0        // ref_novel_view (3,4096)
#define OFF1 12288    // blended_img    (3,4096)
#define OFF2 24576    // interp_view    (4,3,4096)
#define OFF3 73728    // weight         (4,4096,24)
#define OFF4 466944   // confs          (4,4096)

// ---------------------------------------------------------------------------
// Static device-global scratch.
// ---------------------------------------------------------------------------
__device__ unsigned g_cc [NS * NPX * 64];   // [s][p][ch]: lo=ce, hi=ctx (bf16)
__device__ float2 g_fld[NS * NPX];          // per-pixel (Aw, Ac) score fields
__device__ __align__(16) unsigned short g_vin [NPX * VINW];  // bf16
__device__ float g_iv  [NS * NPX * 3];    // [s][p][c]
__device__ float g_clg [NS * NPX];        // confNet logit per (source,pixel)
// transposed weights (lane-coalesced on the fast index)
__device__ float g_fwT [162 * 64];        // [(ic*9+t)][oc]
__device__ float g_cwT [27 * 64];         // [(ic*9+t)][oc]
__device__ float g_pwT [54 * 64];         // [(ic*9+t)][oc]
__device__ __align__(16) unsigned short g_vwT [3 * 9 * VINW];  // bf16, remapped

__device__ __forceinline__ int clampi(int v, int lo, int hi) {
    return v < lo ? lo : (v > hi ? hi : v);
}
__device__ __forceinline__ unsigned bf16_bits(float f) {   // RNE f32->bf16 bits
    unsigned u = __float_as_uint(f);
    return (u + 0x7fffu + ((u >> 16) & 1u)) >> 16;
}
__device__ __forceinline__ float bf16_lo(unsigned v) { return __uint_as_float(v << 16); }
__device__ __forceinline__ float bf16_hi(unsigned v) { return __uint_as_float(v & 0xffff0000u); }
__device__ __forceinline__ float ldbf(const unsigned short* p, int i) {
    return __uint_as_float(((unsigned)p[i]) << 16);
}

// ---------------------------------------------------------------------------
// Kernel 0: weight transposes (same work every call).
// ---------------------------------------------------------------------------
__global__ void k_prep(const float* __restrict__ fw, const float* __restrict__ cw,
                       const float* __restrict__ pw, const float* __restrict__ vw)
{
    const int i = blockIdx.x * 256 + threadIdx.x;
    const int stride = gridDim.x * 256;
    for (int d = i; d < 162 * 64; d += stride) g_fwT[d] = fw[(d & 63) * 162 + (d >> 6)];
    for (int d = i; d < 27 * 64;  d += stride) g_cwT[d] = cw[(d & 63) * 27  + (d >> 6)];
    for (int d = i; d < 54 * 64;  d += stride) g_pwT[d] = pw[(d & 63) * 54  + (d >> 6)];
    for (int d = i; d < 3 * 9 * VINW; d += stride) {
        const int oc = d / (9 * VINW), rem = d % (9 * VINW);
        const int t = rem / VINW, nch = rem % VINW;
        float v = 0.f;
        if (nch < 256)      v = vw[(oc * 515 + 3 + nch) * 9 + t];
        else if (nch < 512) v = vw[(oc * 515 + 259 + (nch - 256)) * 9 + t];
        else if (nch < 515) v = vw[(oc * 515 + (nch - 512)) * 9 + t];
        g_vwT[d] = (unsigned short)bf16_bits(v);
    }
}

// ---------------------------------------------------------------------------
// Kernel 1: flowRefNet + ctxNet convs, HALF-ROW-TILED (2 blocks/CU).
// block = (s, py, half): 256 threads = 4 waves; wave w -> 8 px, lane = oc.
// ---------------------------------------------------------------------------
__global__ __launch_bounds__(256) void k_convs(
    const float* __restrict__ sv, const float* __restrict__ sf, const float* __restrict__ wv,
    const float* __restrict__ flow_b, const float* __restrict__ ctx_b,
    const float* __restrict__ wnet_w, const float* __restrict__ cnet_w)
{
    __shared__ float lds[18 * 3 * HW];
    const int blk = blockIdx.x;
    const int s = blk >> 7, py = (blk & 127) >> 1, half = blk & 1;
    const int tid = threadIdx.x;

    for (int i = tid; i < 18 * 3 * HW; i += 256) {
        const int lc = i % HW;
        const int rr = (i / HW) % 3;
        const int pl = i / (3 * HW);
        const int iy = py + rr - 1;
        const int ix = half * 32 + lc - 1;
        float v = 0.f;
        if ((unsigned)iy < 64u && (unsigned)ix < 64u) {
            const float* src = (pl < 6) ? (sf + (s * 6 + pl) * NPX)
                             : (pl < 9) ? (sv + (s * 3 + (pl - 6)) * NPX)
                                        : (wv + (s * 9 + (pl - 9)) * NPX);
            v = src[iy * 64 + ix];
        }
        lds[i] = v;
    }
    __syncthreads();

    const int oc  = tid & 63;
    const int wid = tid >> 6;
    const int lc0 = wid * 8;

    float acc_ce[8], acc_ctx[8];
    const float fb = flow_b[oc], cb = ctx_b[oc];
    #pragma unroll
    for (int j = 0; j < 8; ++j) { acc_ce[j] = fb; acc_ctx[j] = cb; }

    for (int pl = 0; pl < 18; ++pl) {
        float w[9];
        #pragma unroll
        for (int t = 0; t < 9; ++t) w[t] = g_fwT[(pl * 9 + t) * 64 + oc];
        float wc[9];
        const bool has_ctx = (pl >= 6 && pl < 9);
        if (has_ctx) {
            #pragma unroll
            for (int t = 0; t < 9; ++t) wc[t] = g_cwT[((pl - 6) * 9 + t) * 64 + oc];
        }
        float c0[3], c1[3], c2[3];
        #pragma unroll
        for (int r = 0; r < 3; ++r) {
            c0[r] = lds[(pl * 3 + r) * HW + lc0];
            c1[r] = lds[(pl * 3 + r) * HW + lc0 + 1];
        }
        #pragma unroll
        for (int j = 0; j < 8; ++j) {
            #pragma unroll
            for (int r = 0; r < 3; ++r)
                c2[r] = lds[(pl * 3 + r) * HW + lc0 + j + 2];
            float a = 0.f;
            #pragma unroll
            for (int r = 0; r < 3; ++r)
                a += c0[r] * w[r * 3 + 0] + c1[r] * w[r * 3 + 1] + c2[r] * w[r * 3 + 2];
            acc_ce[j] += a;
            if (has_ctx) {
                float b2 = 0.f;
                #pragma unroll
                for (int r = 0; r < 3; ++r)
                    b2 += c0[r] * wc[r * 3 + 0] + c1[r] * wc[r * 3 + 1] + c2[r] * wc[r * 3 + 2];
                acc_ctx[j] += b2;
            }
            #pragma unroll
            for (int r = 0; r < 3; ++r) { c0[r] = c1[r]; c1[r] = c2[r]; }
        }
    }

    const float Wce = wnet_w[6 + oc], Cce = cnet_w[6 + oc];
    float awsel = 0.f, acsel = 0.f;
    #pragma unroll
    for (int j = 0; j < 8; ++j) {
        const float ce = fmaxf(acc_ce[j], 0.f);
        const float cx = fmaxf(acc_ctx[j], 0.f);
        const int p = py * 64 + half * 32 + wid * 8 + j;
        g_cc[(s * NPX + p) * 64 + oc] = bf16_bits(ce) | (bf16_bits(cx) << 16);
        float gw = ce * Wce, gc = ce * Cce;
        #pragma unroll
        for (int off = 32; off; off >>= 1) {
            gw += __shfl_xor(gw, off, 64);
            gc += __shfl_xor(gc, off, 64);
        }
        awsel = (oc == j) ? gw : awsel;
        acsel = (oc == j) ? gc : acsel;
    }
    if (oc < 8) {
        const int lpx = wid * 8 + oc;
        float fwv = 0.f, fcv = 0.f;
        #pragma unroll
        for (int c = 0; c < 6; ++c) {
            const float v = lds[(c * 3 + 1) * HW + lpx + 1];
            fwv += v * wnet_w[c];
            fcv += v * cnet_w[c];
        }
        g_fld[s * NPX + py * 64 + half * 32 + lpx] = make_float2(awsel + fwv, acsel + fcv);
    }
}

// ---------------------------------------------------------------------------
// Kernel 2: epipolar softmax + interpolations, FIELD-BASED, packed gathers.
// ---------------------------------------------------------------------------
__global__ __launch_bounds__(256) void k_epi(
    const float* __restrict__ sv, const int* __restrict__ nxy,
    const float* __restrict__ spa, const float* __restrict__ ang,
    const float* __restrict__ wnet_w, const float* __restrict__ wnet_b,
    const float* __restrict__ cnet_w,
    float* __restrict__ out)
{
    const int blk = blockIdx.x;
    const int wid = threadIdx.x >> 6;
    const int l   = threadIdx.x & 63;
    const int s   = (blk & 7) >> 1;                       // XCD-pair swizzle
    const int p   = (blk >> 3) * 8 + (blk & 1) * 4 + wid;

    int q[NSZ];
    #pragma unroll
    for (int e = 0; e < 8; ++e) {
        int nx = nxy[((s * NPX + p) * 8 + e) * 2 + 0];
        int ny = nxy[((s * NPX + p) * 8 + e) * 2 + 1];
        nx = clampi(nx, 0, 63);
        #pragma unroll
        for (int k = 0; k < 3; ++k) {
            int y = clampi(ny + k - 1, 0, 63);
            q[e * 3 + k] = y * 64 + nx;
        }
    }

    const unsigned* ccp = g_cc + (size_t)s * NPX * 64;
    unsigned cc[NSZ];
    #pragma unroll
    for (int n = 0; n < NSZ; ++n) cc[n] = ccp[q[n] * 64 + l];

    // lane = channel: mu/var -> base scalars (2-scalar allreduce)
    float mu = 0.f;
    #pragma unroll
    for (int n = 0; n < NSZ; ++n) mu += bf16_lo(cc[n]);
    mu *= (1.f / 24.f);
    float var = 0.f;
    #pragma unroll
    for (int n = 0; n < NSZ; ++n) { const float d = bf16_lo(cc[n]) - mu; var += d * d; }
    var *= (1.f / 23.f);   // ddof=1

    float pw = mu * wnet_w[70 + l] + var * wnet_w[134 + l];
    float pc = mu * cnet_w[70 + l] + var * cnet_w[134 + l];
    #pragma unroll
    for (int off = 32; off; off >>= 1) {
        pw += __shfl_xor(pw, off, 64);
        pc += __shfl_xor(pc, off, 64);
    }
    const float base_w = pw, base_c = pc;

    // lane = band element: field gather + spa/ang terms -> logit
    float Aw = 0.f, Ac = 0.f;
    if (l < NSZ) {
        const float2 A = g_fld[s * NPX + q[l]];
        Aw = A.x; Ac = A.y;
        #pragma unroll
        for (int c = 0; c < 2; ++c) {
            const float v = spa[((s * 2 + c) * NSZ + l) * NPX + p];
            Aw += v * wnet_w[198 + c];
            Ac += v * cnet_w[198 + c];
        }
        #pragma unroll
        for (int c = 0; c < 6; ++c) {
            const float v = ang[((s * 6 + c) * NSZ + l) * NPX + p];
            Aw += v * wnet_w[200 + c];
            Ac += v * cnet_w[200 + c];
        }
    }

    // softmax over the 24 active lanes
    float logit = (l < NSZ) ? (Aw + base_w + wnet_b[0]) : -1e30f;
    float mx = logit;
    #pragma unroll
    for (int off = 32; off; off >>= 1) mx = fmaxf(mx, __shfl_xor(mx, off, 64));
    float e = (l < NSZ) ? __expf(logit - mx) : 0.f;
    float ssum = e;
    #pragma unroll
    for (int off = 32; off; off >>= 1) ssum += __shfl_xor(ssum, off, 64);
    const float wgt = e / ssum;

    // confNet logit (Σwgt = 1 makes the base additive)
    float clp = (l < NSZ) ? (Ac + base_c) * wgt : 0.f;
    #pragma unroll
    for (int off = 32; off; off >>= 1) clp += __shfl_xor(clp, off, 64);
    if (l == 0) g_clg[s * NPX + p] = clp;

    // out3: weight [s][p][n]
    if (l < NSZ) out[OFF3 + (s * NPX + p) * NSZ + l] = wgt;

    // broadcast all 24 weights
    float wall[NSZ];
    #pragma unroll
    for (int n = 0; n < NSZ; ++n) wall[n] = __shfl(wgt, n, 64);

    // interp_ctx channel l (hi halves of the same gathered dwords)
    float sc = 0.f;
    #pragma unroll
    for (int n = 0; n < NSZ; ++n) sc += bf16_hi(cc[n]) * wall[n];
    g_vin[p * VINW + s * 64 + l] = (unsigned short)bf16_bits(sc);   // ictx base 0

    // interp_view (lanes 0..2)
    if (l < 3) {
        float svv = 0.f;
        #pragma unroll
        for (int n = 0; n < NSZ; ++n) svv += sv[(s * 3 + l) * NPX + q[n]] * wall[n];
        g_iv[(s * NPX + p) * 3 + l] = svv;
        out[OFF2 + (s * 3 + l) * NPX + p] = svv;
    }
}

// ---------------------------------------------------------------------------
// Kernel 3: psvNet + FUSED confNet/blend, HALF-ROW-TILED.
// ---------------------------------------------------------------------------
__global__ __launch_bounds__(256) void k_psv(
    const float* __restrict__ psvs, const float* __restrict__ psv_b,
    const float* __restrict__ cnet_b, float* __restrict__ out)
{
    __shared__ float lds[27 * 3 * HW];
    const int blk = blockIdx.x;
    const int s = blk >> 7, py = (blk & 127) >> 1, half = blk & 1;
    const int tid = threadIdx.x;

    for (int i = tid; i < 27 * 3 * HW; i += 256) {
        const int lc = i % HW;
        const int rr = (i / HW) % 3;
        const int pl = i / (3 * HW);
        float v = 0.f;
        if (pl < 24) {
            const int iy = py + rr - 1;
            const int ix = half * 32 + lc - 1;
            if ((unsigned)iy < 64u && (unsigned)ix < 64u)
                v = psvs[(s * 24 + pl) * NPX + iy * 64 + ix];
        }
        lds[i] = v;
    }
    __syncthreads();

    if (tid < 3 * HW) {
        const int r = tid / HW, lc = tid % HW;
        const int iy = py + r - 1, ix = half * 32 + lc - 1;
        if ((unsigned)iy < 64u && (unsigned)ix < 64u) {
            const int p = iy * 64 + ix;
            const float cb2 = cnet_b[0];
            float lg[NS];
            #pragma unroll
            for (int ss = 0; ss < NS; ++ss) lg[ss] = g_clg[ss * NPX + p] + cb2;
            float m = lg[0];
            #pragma unroll
            for (int ss = 1; ss < NS; ++ss) m = fmaxf(m, lg[ss]);
            float ssum = 0.f;
            float conf[NS];
            #pragma unroll
            for (int ss = 0; ss < NS; ++ss) { conf[ss] = __expf(lg[ss] - m); ssum += conf[ss]; }
            const float inv = 1.f / ssum;
            #pragma unroll
            for (int ss = 0; ss < NS; ++ss) conf[ss] *= inv;
            float bl[3];
            #pragma unroll
            for (int c = 0; c < 3; ++c) {
                float a = 0.f;
                #pragma unroll
                for (int ss = 0; ss < NS; ++ss)
                    a += g_iv[(ss * NPX + p) * 3 + c] * conf[ss];
                bl[c] = a;
                lds[((24 + c) * 3 + r) * HW + lc] = a;
            }
            if (s == 0 && r == 1 && lc >= 1 && lc <= 32) {
                #pragma unroll
                for (int ss = 0; ss < NS; ++ss) out[OFF4 + ss * NPX + p] = conf[ss];
                #pragma unroll
                for (int c = 0; c < 3; ++c) {
                    out[OFF1 + c * NPX + p] = bl[c];
                    g_vin[p * VINW + 512 + c] = (unsigned short)bf16_bits(bl[c]);
                }
            }
        }
    }
    __syncthreads();

    const int oc  = tid & 63;
    const int wid = tid >> 6;
    const int lc0 = wid * 8;
    const float bias = psv_b[oc];

    float wp[3][9];
    #pragma unroll
    for (int ic = 0; ic < 3; ++ic)
        #pragma unroll
        for (int t = 0; t < 9; ++t) wp[ic][t] = g_pwT[(ic * 9 + t) * 64 + oc];

    float bconst[8];
    #pragma unroll
    for (int j = 0; j < 8; ++j) bconst[j] = bias;
    for (int ic = 0; ic < 3; ++ic) {
        float w[9];
        #pragma unroll
        for (int t = 0; t < 9; ++t) w[t] = g_pwT[((3 + ic) * 9 + t) * 64 + oc];
        const int pl = 24 + ic;
        float c0[3], c1[3], c2[3];
        #pragma unroll
        for (int r = 0; r < 3; ++r) {
            c0[r] = lds[(pl * 3 + r) * HW + lc0];
            c1[r] = lds[(pl * 3 + r) * HW + lc0 + 1];
        }
        #pragma unroll
        for (int j = 0; j < 8; ++j) {
            #pragma unroll
            for (int r = 0; r < 3; ++r)
                c2[r] = lds[(pl * 3 + r) * HW + lc0 + j + 2];
            float a = 0.f;
            #pragma unroll
            for (int r = 0; r < 3; ++r)
                a += c0[r] * w[r * 3 + 0] + c1[r] * w[r * 3 + 1] + c2[r] * w[r * 3 + 2];
            bconst[j] += a;
            #pragma unroll
            for (int r = 0; r < 3; ++r) { c0[r] = c1[r]; c1[r] = c2[r]; }
        }
    }

    float acc[8];
    #pragma unroll
    for (int j = 0; j < 8; ++j) acc[j] = 0.f;

    for (int d = 0; d < 8; ++d) {
        float a[8];
        #pragma unroll
        for (int j = 0; j < 8; ++j) a[j] = bconst[j];
        #pragma unroll
        for (int ic = 0; ic < 3; ++ic) {
            const int pl = ic * 8 + d;
            float c0[3], c1[3], c2[3];
            #pragma unroll
            for (int r = 0; r < 3; ++r) {
                c0[r] = lds[(pl * 3 + r) * HW + lc0];
                c1[r] = lds[(pl * 3 + r) * HW + lc0 + 1];
            }
            #pragma unroll
            for (int j = 0; j < 8; ++j) {
                #pragma unroll
                for (int r = 0; r < 3; ++r)
                    c2[r] = lds[(pl * 3 + r) * HW + lc0 + j + 2];
                float t2 = 0.f;
                #pragma unroll
                for (int r = 0; r < 3; ++r)
                    t2 += c0[r] * wp[ic][r * 3 + 0] + c1[r] * wp[ic][r * 3 + 1] + c2[r] * wp[ic][r * 3 + 2];
                a[j] += t2;
                #pragma unroll
                for (int r = 0; r < 3; ++r) { c0[r] = c1[r]; c1[r] = c2[r]; }
            }
        }
        #pragma unroll
        for (int j = 0; j < 8; ++j) acc[j] += fmaxf(a[j], 0.f);
    }
    #pragma unroll
    for (int j = 0; j < 8; ++j)
        g_vin[(py * 64 + half * 32 + wid * 8 + j) * VINW + 256 + s * 64 + oc] =
            (unsigned short)bf16_bits(acc[j] * 0.125f);
}

// ---------------------------------------------------------------------------
// Kernel 4: vref conv3x3 over 515 channels -> 3, VECTORIZED (uint4 = 8 bf16).
// ---------------------------------------------------------------------------
__global__ __launch_bounds__(64) void k_vref(
    const float* __restrict__ vref_b, float* __restrict__ out)
{
    const int p = blockIdx.x;
    const int py = p >> 6, px = p & 63;
    const int l = threadIdx.x;

    float acc[3] = {0.f, 0.f, 0.f};
    #pragma unroll
    for (int t = 0; t < 9; ++t) {
        const int iy = py + t / 3 - 1, ix = px + t % 3 - 1;
        if ((unsigned)iy >= 64u || (unsigned)ix >= 64u) continue;
        const int rowbase = (iy * 64 + ix) * VINW;
        const uint4 vv = *(const uint4*)(g_vin + rowbase + 8 * l);
        float v[8];
        v[0] = bf16_lo(vv.x); v[1] = bf16_hi(vv.x);
        v[2] = bf16_lo(vv.y); v[3] = bf16_hi(vv.y);
        v[4] = bf16_lo(vv.z); v[5] = bf16_hi(vv.z);
        v[6] = bf16_lo(vv.w); v[7] = bf16_hi(vv.w);
        #pragma unroll
        for (int oc = 0; oc < 3; ++oc) {
            const uint4 ww = *(const uint4*)(g_vwT + (oc * 9 + t) * VINW + 8 * l);
            acc[oc] += v[0] * bf16_lo(ww.x) + v[1] * bf16_hi(ww.x)
                     + v[2] * bf16_lo(ww.y) + v[3] * bf16_hi(ww.y)
                     + v[4] * bf16_lo(ww.z) + v[5] * bf16_hi(ww.z)
                     + v[6] * bf16_lo(ww.w) + v[7] * bf16_hi(ww.w);
        }
        if (l < 3) {   // blended channels 512-514
            const float bv = ldbf(g_vin, rowbase + 512 + l);
            #pragma unroll
            for (int oc = 0; oc < 3; ++oc)
                acc[oc] += bv * ldbf(g_vwT, (oc * 9 + t) * VINW + 512 + l);
        }
    }
    #pragma unroll
    for (int off = 32; off; off >>= 1) {
        #pragma unroll
        for (int oc = 0; oc < 3; ++oc)
            acc[oc] += __shfl_xor(acc[oc], off, 64);
    }
    if (l == 0) {
        #pragma unroll
        for (int oc = 0; oc < 3; ++oc)
            out[OFF0 + oc * NPX + p] = acc[oc] + vref_b[oc];
    }
}

// ---------------------------------------------------------------------------
extern "C" void kernel_launch(void* const* d_in, const int* in_sizes, int n_in,
                              void* d_out, int out_size, void* d_ws, size_t ws_size,
                              hipStream_t stream)
{
    auto find1 = [&](int sz, int fb) -> int {
        for (int i = 0; i < n_in; ++i) if (in_sizes[i] == sz) return i;
        return fb;
    };
    const int i_sv  = find1(49152, 0);
    const int i_sf  = find1(98304, 1);
    const int i_psv = find1(393216, 2);
    const int i_wv  = find1(147456, 3);
    const int i_nxy = find1(262144, 5);
    const int i_spa = find1(786432, 6);
    const int i_ang = find1(2359296, 7);
    const int i_fw  = find1(10368, 9);
    const int i_cw  = find1(1728, 11);
    const int i_pw  = find1(3456, 17);
    const int i_vw  = find1(13905, 19);
    const int i_vb  = find1(3, 20);
    int i_ww = -1, i_cnw = -1;
    for (int i = 0; i < n_in; ++i)
        if (in_sizes[i] == 206) { if (i_ww < 0) i_ww = i; else { i_cnw = i; break; } }
    if (i_ww  < 0) i_ww  = 13;
    if (i_cnw < 0) i_cnw = 15;
    int b64[3] = {10, 12, 18}; int c64 = 0;
    for (int i = 0; i < n_in && c64 < 3; ++i) if (in_sizes[i] == 64) b64[c64++] = i;
    const int i_fb = b64[0], i_cb = b64[1], i_pb = b64[2];
    int i_wb = -1, i_cnb = -1;
    for (int i = i_fw + 1; i < n_in; ++i)
        if (in_sizes[i] == 1) { if (i_wb < 0) i_wb = i; else { i_cnb = i; break; } }
    if (i_wb  < 0) i_wb  = 14;
    if (i_cnb < 0) i_cnb = 16;

    const float* sv     = (const float*)d_in[i_sv];
    const float* sf     = (const float*)d_in[i_sf];
    const float* psvs   = (const float*)d_in[i_psv];
    const float* wv     = (const float*)d_in[i_wv];
    const int*   nxy    = (const int*)d_in[i_nxy];
    const float* spa    = (const float*)d_in[i_spa];
    const float* ang    = (const float*)d_in[i_ang];
    const float* flow_w = (const float*)d_in[i_fw];
    const float* flow_b = (const float*)d_in[i_fb];
    const float* ctx_w  = (const float*)d_in[i_cw];
    const float* ctx_b  = (const float*)d_in[i_cb];
    const float* wnet_w = (const float*)d_in[i_ww];
    const float* wnet_b = (const float*)d_in[i_wb];
    const float* cnet_w = (const float*)d_in[i_cnw];
    const float* cnet_b = (const float*)d_in[i_cnb];
    const float* psv_w  = (const float*)d_in[i_pw];
    const float* psv_b  = (const float*)d_in[i_pb];
    const float* vref_w = (const float*)d_in[i_vw];
    const float* vref_b = (const float*)d_in[i_vb];
    (void)d_ws; (void)ws_size; (void)out_size;

    float* out = (float*)d_out;

    k_prep <<<64, 256, 0, stream>>>(flow_w, ctx_w, psv_w, vref_w);
    k_convs<<<512, 256, 0, stream>>>(sv, sf, wv, flow_b, ctx_b, wnet_w, cnet_w);
    k_epi  <<<4096, 256, 0, stream>>>(sv, nxy, spa, ang, wnet_w, wnet_b, cnet_w, out);
    k_psv  <<<512, 256, 0, stream>>>(psvs, psv_b, cnet_b, out);
    k_vref <<<4096, 64, 0, stream>>>(vref_b, out);
}